// Round 2
// baseline (488.274 us; speedup 1.0000x reference)
//
#include <hip/hip_runtime.h>
#include <hip/hip_bf16.h>
#include <math.h>

// Problem constants (fixed by reference setup_inputs)
#define HWN 2304          // H*W
#define CC  256           // channels
#define NHD 8             // heads
#define CHD 32            // channels per head
#define NJS 8             // j-range splits for attention
#define JCH (HWN / NJS)   // 288 j per split
#define NCHK (JCH / 48)   // 6 chunks of 48 per split
#define ROWS 256          // q rows per workgroup
#define NRT (HWN / ROWS)  // 9 row tiles

// workspace layout (float offsets)
#define QT_OFF 0
#define KT_OFF (2 * HWN * CC)                  // 1179648
#define VT_OFF (4 * HWN * CC)
#define OP_OFF (6 * HWN * CC)                  // 3538944
#define OPSZ   (2 * NHD * NJS * HWN * CHD)     // 9437184
#define LP_OFF (OP_OFF + OPSZ)
#define LPSZ   (2 * NHD * NJS * HWN)           // 294912
#define BD_OFF (LP_OFF + LPSZ)

// ---------------------------------------------------------------------------
// Kernel A: 1x1-conv projections. out_t[b][n][o] = sum_c W[o][c]*in[b][c][n] + bias[o]
// which: 0->Q(from x), 1->K(from y), 2->V(from y)
// ---------------------------------------------------------------------------
__global__ __launch_bounds__(256) void proj_kernel(
    const float* __restrict__ x, const float* __restrict__ y,
    const float* __restrict__ wq, const float* __restrict__ bq,
    const float* __restrict__ wk, const float* __restrict__ bk,
    const float* __restrict__ wv, const float* __restrict__ bv,
    float* __restrict__ ws)
{
    const int nb = blockIdx.x * 64;
    const int ob = blockIdx.y * 64;
    const int z  = blockIdx.z;
    const int b = z / 3, which = z % 3;
    const float* in  = (which == 0) ? x : y;
    const float* W   = (which == 0) ? wq : (which == 1) ? wk : wv;
    const float* bia = (which == 0) ? bq : (which == 1) ? bk : bv;
    float* out = ws + (size_t)which * (2 * HWN * CC) + (size_t)b * HWN * CC;

    __shared__ float Xs[64][68];   // [c_local][n_local]
    __shared__ float Wn[64][68];   // [o_local][c_local] (natural)

    const int t  = threadIdx.x;
    const int tn = t & 15, to = t >> 4;
    float acc[4][4] = {};   // [o4][n4]

    for (int cc = 0; cc < CC; cc += 64) {
        const int r   = t >> 4;
        const int col = (t & 15) * 4;
        #pragma unroll
        for (int rr = 0; rr < 4; rr++) {
            const int row = r + rr * 16;
            *(float4*)&Xs[row][col] =
                *(const float4*)&in[((size_t)b * CC + cc + row) * HWN + nb + col];
            *(float4*)&Wn[row][col] =
                *(const float4*)&W[(size_t)(ob + row) * CC + cc + col];
        }
        __syncthreads();
        #pragma unroll 4
        for (int k = 0; k < 64; k++) {
            float av[4];
            #pragma unroll
            for (int i2 = 0; i2 < 4; i2++) av[i2] = Wn[to * 4 + i2][k];
            const float4 b4 = *(const float4*)&Xs[k][tn * 4];
            const float bv4[4] = {b4.x, b4.y, b4.z, b4.w};
            #pragma unroll
            for (int i2 = 0; i2 < 4; i2++)
                #pragma unroll
                for (int j2 = 0; j2 < 4; j2++)
                    acc[i2][j2] = fmaf(av[i2], bv4[j2], acc[i2][j2]);
        }
        __syncthreads();
    }
    float bb[4];
    *(float4*)bb = *(const float4*)&bia[ob + to * 4];
    #pragma unroll
    for (int j2 = 0; j2 < 4; j2++) {
        const int n = nb + tn * 4 + j2;
        float4 vo = { acc[0][j2] + bb[0], acc[1][j2] + bb[1],
                      acc[2][j2] + bb[2], acc[3][j2] + bb[3] };
        *(float4*)&out[(size_t)n * CC + ob + to * 4] = vo;
    }
}

// ---------------------------------------------------------------------------
// Kernel B: softmax-bound constants. bounds[bh] = max_j ||k_j|| (per b,head);
// bounds[16] = max_d ||w_emb[d]|| + max_d ||h_emb[d]||
// ---------------------------------------------------------------------------
__global__ __launch_bounds__(256) void bounds_kernel(
    const float* __restrict__ h_emb, const float* __restrict__ w_emb,
    float* __restrict__ ws)
{
    const float* Kt = ws + KT_OFF;
    float* bounds = ws + BD_OFF;
    __shared__ float red[256];
    const int t = threadIdx.x;
    const int bh = blockIdx.x;
    if (bh < 16) {
        const int b = bh >> 3, h = bh & 7;
        float mx = 0.f;
        for (int j = t; j < HWN; j += 256) {
            const float* kp = &Kt[((size_t)b * HWN + j) * CC + h * CHD];
            float s = 0.f;
            #pragma unroll
            for (int c = 0; c < CHD; c += 4) {
                float4 v = *(const float4*)&kp[c];
                s += v.x * v.x + v.y * v.y + v.z * v.z + v.w * v.w;
            }
            mx = fmaxf(mx, s);
        }
        red[t] = mx; __syncthreads();
        for (int s2 = 128; s2 > 0; s2 >>= 1) {
            if (t < s2) red[t] = fmaxf(red[t], red[t + s2]);
            __syncthreads();
        }
        if (t == 0) bounds[bh] = sqrtf(red[0]);
    } else {
        float mw = 0.f, mh = 0.f;
        if (t < 95) {
            float s = 0.f;
            for (int c = 0; c < CHD; c++) { float v = w_emb[t * CHD + c]; s += v * v; }
            mw = s;
            s = 0.f;
            for (int c = 0; c < CHD; c++) { float v = h_emb[t * CHD + c]; s += v * v; }
            mh = s;
        }
        red[t] = mw; __syncthreads();
        for (int s2 = 128; s2 > 0; s2 >>= 1) {
            if (t < s2) red[t] = fmaxf(red[t], red[t + s2]);
            __syncthreads();
        }
        const float rw = red[0]; __syncthreads();
        red[t] = mh; __syncthreads();
        for (int s2 = 128; s2 > 0; s2 >>= 1) {
            if (t < s2) red[t] = fmaxf(red[t], red[t + s2]);
            __syncthreads();
        }
        if (t == 0) bounds[16] = sqrtf(rw) + sqrtf(red[0]);
    }
}

// ---------------------------------------------------------------------------
// Kernel C: fused attention (bound-based softmax, no online max).
// grid (NJS, NRT, 16). One lane owns one q row; 48-j chunks (one image row).
// Writes partial (O, l) per j-split.
// ---------------------------------------------------------------------------
__global__ __launch_bounds__(256, 2) void attn_kernel(
    const float* __restrict__ h_emb, const float* __restrict__ w_emb,
    float* __restrict__ ws)
{
    const float* Qt = ws + QT_OFF;
    const float* Kt = ws + KT_OFF;
    const float* Vt = ws + VT_OFF;
    float* OP = ws + OP_OFF;
    float* LP = ws + LP_OFF;
    const float* bounds = ws + BD_OFF;

    const int js = blockIdx.x;
    const int rt = blockIdx.y;
    const int bh = blockIdx.z;
    const int b = bh >> 3, h = bh & 7;

    __shared__ unsigned short qws[256 * 98];  // per-row qw table, bf16
    __shared__ float hs[95 * 36];             // h_emb staged [d][36]
    __shared__ float un[95 * 36];             // union: w_emb stage OR K/V chunk

    const int t = threadIdx.x;
    const int i = rt * ROWS + t;              // global q row
    const int xi = i % 48, yi = i / 48;

    // stage w_emb (into un) and h_emb
    for (int idx = t; idx < 95 * 8; idx += 256) {
        const int d = idx >> 3, c4 = (idx & 7) * 4;
        *(float4*)&un[d * 36 + c4] = *(const float4*)&w_emb[d * CHD + c4];
        *(float4*)&hs[d * 36 + c4] = *(const float4*)&h_emb[d * CHD + c4];
    }
    // load q row to registers
    float q[CHD];
    {
        const float* qp = &Qt[((size_t)b * HWN + i) * CC + h * CHD];
        #pragma unroll
        for (int c = 0; c < CHD; c += 4)
            *(float4*)&q[c] = *(const float4*)&qp[c];
    }
    float qn2 = 0.f;
    #pragma unroll
    for (int c = 0; c < CHD; c++) qn2 = fmaf(q[c], q[c], qn2);
    const float c1 = 0.09016844005556021f;     // log2(e) / 16
    const float mbound = sqrtf(qn2) * (bounds[bh] + bounds[16]);
    const float c0 = -mbound * c1;

    __syncthreads();   // w_emb/h_emb staged

    // per-row qw table: qw[d] = q . w_emb[d], d in [0,95)
    for (int d = 0; d < 95; d++) {
        float s = 0.f;
        #pragma unroll
        for (int c = 0; c < CHD; c += 4) {
            const float4 w4 = *(const float4*)&un[d * 36 + c];
            s = fmaf(q[c], w4.x, s);   s = fmaf(q[c + 1], w4.y, s);
            s = fmaf(q[c + 2], w4.z, s); s = fmaf(q[c + 3], w4.w, s);
        }
        const unsigned int bits = __float_as_uint(s);
        qws[t * 98 + d] =
            (unsigned short)((bits + 0x7FFFu + ((bits >> 16) & 1u)) >> 16);
    }
    __syncthreads();   // done reading un (w_emb) before K/V overwrites

    float O[CHD] = {};
    float l = 0.f;
    float* Ks = un;
    float* Vs = un + 48 * 32;
    const unsigned short* qwrow = &qws[t * 98];

    for (int ch = 0; ch < NCHK; ch++) {
        const int j0 = js * JCH + ch * 48;
        const int yj = j0 / 48;
        for (int idx = t; idx < 384; idx += 256) {
            const int row = idx >> 3, c4 = (idx & 7) * 4;
            const size_t g = ((size_t)b * HWN + j0 + row) * CC + h * CHD + c4;
            *(float4*)&Ks[row * 32 + c4] = *(const float4*)&Kt[g];
            *(float4*)&Vs[row * 32 + c4] = *(const float4*)&Vt[g];
        }
        __syncthreads();
        // qh for this chunk (dy constant over the 48 j's)
        const int dy = yj - yi + 47;
        float qh = 0.f;
        #pragma unroll
        for (int c = 0; c < CHD; c += 4) {
            const float4 h4 = *(const float4*)&hs[dy * 36 + c];
            qh = fmaf(q[c], h4.x, qh);     qh = fmaf(q[c + 1], h4.y, qh);
            qh = fmaf(q[c + 2], h4.z, qh); qh = fmaf(q[c + 3], h4.w, qh);
        }
        #pragma unroll 2
        for (int jj = 0; jj < 48; jj++) {
            const float* kr = &Ks[jj * 32];
            float t0 = 0.f, t1 = 0.f, t2 = 0.f, t3 = 0.f;
            #pragma unroll
            for (int c = 0; c < CHD; c += 4) {
                const float4 k4 = *(const float4*)&kr[c];
                t0 = fmaf(q[c], k4.x, t0);
                t1 = fmaf(q[c + 1], k4.y, t1);
                t2 = fmaf(q[c + 2], k4.z, t2);
                t3 = fmaf(q[c + 3], k4.w, t3);
            }
            const int dx = jj - xi + 47;
            const float qwv = __uint_as_float(((unsigned)qwrow[dx]) << 16);
            const float s = ((t0 + t1) + (t2 + t3)) + qh + qwv;
            const float p = __builtin_amdgcn_exp2f(fmaf(s, c1, c0));
            l += p;
            const float* vr = &Vs[jj * 32];
            #pragma unroll
            for (int c = 0; c < CHD; c += 4) {
                const float4 v4 = *(const float4*)&vr[c];
                O[c]     = fmaf(p, v4.x, O[c]);
                O[c + 1] = fmaf(p, v4.y, O[c + 1]);
                O[c + 2] = fmaf(p, v4.z, O[c + 2]);
                O[c + 3] = fmaf(p, v4.w, O[c + 3]);
            }
        }
        __syncthreads();
    }
    float* op = &OP[(((size_t)bh * NJS + js) * HWN + i) * CHD];
    #pragma unroll
    for (int c = 0; c < CHD; c += 4) *(float4*)&op[c] = *(float4*)&O[c];
    LP[((size_t)bh * NJS + js) * HWN + i] = l;
}

// ---------------------------------------------------------------------------
// Kernel D: merge partials, normalize, output projection + bias.
// out[b][o][n] = sum_c wo[o][c] * (sum_js OP / sum_js l) + bo[o]
// ---------------------------------------------------------------------------
__global__ __launch_bounds__(256) void out_kernel(
    const float* __restrict__ wo, const float* __restrict__ bo,
    const float* __restrict__ ws, float* __restrict__ out)
{
    const float* OP = ws + OP_OFF;
    const float* LP = ws + LP_OFF;
    const int nb = blockIdx.x * 64;
    const int ob = blockIdx.y * 64;
    const int b  = blockIdx.z;

    __shared__ float As[64][68];    // [c_local][n_local]
    __shared__ float Wn[64][68];    // [o_local][c_local]
    __shared__ float linv[2][64];

    const int t = threadIdx.x;
    const int tn = t & 15, to = t >> 4;
    float acc[4][4] = {};

    for (int ci = 0; ci < 4; ci++) {           // 64-channel chunks = 2 heads
        const int h0 = ci * 2;
        if (t < 128) {
            const int h_l = t >> 6, i_l = t & 63;
            float s = 0.f;
            #pragma unroll
            for (int jsv = 0; jsv < NJS; jsv++)
                s += LP[(((size_t)(b * NHD + h0 + h_l)) * NJS + jsv) * HWN + nb + i_l];
            linv[h_l][i_l] = 1.f / s;
        }
        __syncthreads();
        // stage As: 1024 float4 slots (16 cq x 64 n)
        for (int slot = t; slot < 1024; slot += 256) {
            const int n_l = slot >> 4, cq = slot & 15;
            const int h_l = cq >> 3, c_in = (cq & 7) * 4;
            float4 v = {0.f, 0.f, 0.f, 0.f};
            #pragma unroll
            for (int jsv = 0; jsv < NJS; jsv++) {
                const float4 u = *(const float4*)&OP[
                    ((((size_t)(b * NHD + h0 + h_l)) * NJS + jsv) * HWN + nb + n_l) * CHD + c_in];
                v.x += u.x; v.y += u.y; v.z += u.z; v.w += u.w;
            }
            const float li = linv[h_l][n_l];
            As[cq * 4 + 0][n_l] = v.x * li;
            As[cq * 4 + 1][n_l] = v.y * li;
            As[cq * 4 + 2][n_l] = v.z * li;
            As[cq * 4 + 3][n_l] = v.w * li;
        }
        // stage Wo tile (natural layout)
        {
            const int r = t >> 4, col = (t & 15) * 4;
            #pragma unroll
            for (int rr = 0; rr < 4; rr++) {
                const int row = r + rr * 16;
                *(float4*)&Wn[row][col] =
                    *(const float4*)&wo[(size_t)(ob + row) * CC + ci * 64 + col];
            }
        }
        __syncthreads();
        #pragma unroll 4
        for (int k = 0; k < 64; k++) {
            float av[4];
            #pragma unroll
            for (int i2 = 0; i2 < 4; i2++) av[i2] = Wn[to * 4 + i2][k];
            const float4 b4 = *(const float4*)&As[k][tn * 4];
            const float bv4[4] = {b4.x, b4.y, b4.z, b4.w};
            #pragma unroll
            for (int i2 = 0; i2 < 4; i2++)
                #pragma unroll
                for (int j2 = 0; j2 < 4; j2++)
                    acc[i2][j2] = fmaf(av[i2], bv4[j2], acc[i2][j2]);
        }
        __syncthreads();
    }
    #pragma unroll
    for (int i2 = 0; i2 < 4; i2++) {
        const int o = ob + to * 4 + i2;
        const float bb = bo[o];
        float4 vo = { acc[i2][0] + bb, acc[i2][1] + bb,
                      acc[i2][2] + bb, acc[i2][3] + bb };
        *(float4*)&out[((size_t)b * CC + o) * HWN + nb + tn * 4] = vo;
    }
}

// ---------------------------------------------------------------------------
extern "C" void kernel_launch(void* const* d_in, const int* in_sizes, int n_in,
                              void* d_out, int out_size, void* d_ws, size_t ws_size,
                              hipStream_t stream) {
    const float* x     = (const float*)d_in[0];
    const float* y     = (const float*)d_in[1];
    const float* wq    = (const float*)d_in[2];
    const float* bq    = (const float*)d_in[3];
    const float* wk    = (const float*)d_in[4];
    const float* bk    = (const float*)d_in[5];
    const float* wv    = (const float*)d_in[6];
    const float* bv    = (const float*)d_in[7];
    const float* wo    = (const float*)d_in[8];
    const float* bo    = (const float*)d_in[9];
    const float* h_emb = (const float*)d_in[10];
    const float* w_emb = (const float*)d_in[11];
    float* ws  = (float*)d_ws;
    float* out = (float*)d_out;

    dim3 gA(HWN / 64, CC / 64, 6);
    proj_kernel<<<gA, 256, 0, stream>>>(x, y, wq, bq, wk, bk, wv, bv, ws);
    bounds_kernel<<<17, 256, 0, stream>>>(h_emb, w_emb, ws);
    dim3 gC(NJS, NRT, 16);
    attn_kernel<<<gC, 256, 0, stream>>>(h_emb, w_emb, ws);
    dim3 gD(HWN / 64, CC / 64, 2);
    out_kernel<<<gD, 256, 0, stream>>>(wo, bo, ws, out);
}

// Round 3
// 256.476 us; speedup vs baseline: 1.9038x; 1.9038x over previous
//
#include <hip/hip_runtime.h>
#include <hip/hip_bf16.h>
#include <math.h>

// Problem constants (fixed by reference setup_inputs)
#define HWN 2304          // H*W
#define CC  256           // channels
#define NHD 8             // heads
#define CHD 32            // channels per head

// workspace layout (float offsets)
#define QT_OFF 0
#define KT_OFF (2 * HWN * CC)                   // 1179648
#define OP_OFF (2 * KT_OFF)                     // 2359296
#define KBH_OFF (OP_OFF + 16 * HWN * CHD)       // 3538944
#define KBL_OFF (KBH_OFF + (16 * HWN * CHD) / 2)
#define VBH_OFF (KBL_OFF + (16 * HWN * CHD) / 2)
#define VBL_OFF (VBH_OFF + (16 * HWN * CHD) / 2)
#define BD_OFF  (VBL_OFF + (16 * HWN * CHD) / 2)

typedef __attribute__((ext_vector_type(8))) short bf16x8;
typedef __attribute__((ext_vector_type(4))) short bf16x4;
typedef __attribute__((ext_vector_type(4))) float f32x4;

__device__ inline unsigned short bf16_rne(float f) {
    unsigned int u = __float_as_uint(f);
    unsigned int r = u + 0x7FFFu + ((u >> 16) & 1u);
    return (unsigned short)(r >> 16);
}
__device__ inline float bf16_to_f(unsigned short h) {
    return __uint_as_float(((unsigned int)h) << 16);
}

__device__ inline f32x4 mfma32(bf16x8 a, bf16x8 b, f32x4 c) {
    return __builtin_amdgcn_mfma_f32_16x16x32_bf16(a, b, c, 0, 0, 0);
}
__device__ inline f32x4 mfma16(bf16x4 a, bf16x4 b, f32x4 c) {
#if __has_builtin(__builtin_amdgcn_mfma_f32_16x16x16bf16_1k)
    return __builtin_amdgcn_mfma_f32_16x16x16bf16_1k(a, b, c, 0, 0, 0);
#else
    f32x4 d;
    asm volatile("v_mfma_f32_16x16x16_bf16 %0, %1, %2, %3"
                 : "=v"(d) : "v"(a), "v"(b), "v"(c));
    return d;
#endif
}

// ---------------------------------------------------------------------------
// Kernel A: 1x1-conv projections. which: 0->Q(f32), 1->K(f32 + bf16 hi/lo),
// 2->V (bf16 hi/lo transposed only).
// f32 layout: [b][n][256]. Kb: [bh][j][32] bf16. Vb: [bh][c][2304] bf16.
// ---------------------------------------------------------------------------
__global__ __launch_bounds__(256) void proj_kernel(
    const float* __restrict__ x, const float* __restrict__ y,
    const float* __restrict__ wq, const float* __restrict__ bq,
    const float* __restrict__ wk, const float* __restrict__ bk,
    const float* __restrict__ wv, const float* __restrict__ bv,
    float* __restrict__ ws)
{
    const int nb = blockIdx.x * 64;
    const int ob = blockIdx.y * 64;
    const int z  = blockIdx.z;
    const int b = z / 3, which = z % 3;
    const float* in  = (which == 0) ? x : y;
    const float* W   = (which == 0) ? wq : (which == 1) ? wk : wv;
    const float* bia = (which == 0) ? bq : (which == 1) ? bk : bv;

    __shared__ float Xs[64][68];   // [c_local][n_local]
    __shared__ float Wn[64][68];   // [o_local][c_local]

    const int t  = threadIdx.x;
    const int tn = t & 15, to = t >> 4;
    float acc[4][4] = {};   // [o4][n4]

    for (int cc = 0; cc < CC; cc += 64) {
        const int r   = t >> 4;
        const int col = (t & 15) * 4;
        #pragma unroll
        for (int rr = 0; rr < 4; rr++) {
            const int row = r + rr * 16;
            *(float4*)&Xs[row][col] =
                *(const float4*)&in[((size_t)b * CC + cc + row) * HWN + nb + col];
            *(float4*)&Wn[row][col] =
                *(const float4*)&W[(size_t)(ob + row) * CC + cc + col];
        }
        __syncthreads();
        #pragma unroll 4
        for (int k = 0; k < 64; k++) {
            float av[4];
            #pragma unroll
            for (int i2 = 0; i2 < 4; i2++) av[i2] = Wn[to * 4 + i2][k];
            const float4 b4 = *(const float4*)&Xs[k][tn * 4];
            const float bv4[4] = {b4.x, b4.y, b4.z, b4.w};
            #pragma unroll
            for (int i2 = 0; i2 < 4; i2++)
                #pragma unroll
                for (int j2 = 0; j2 < 4; j2++)
                    acc[i2][j2] = fmaf(av[i2], bv4[j2], acc[i2][j2]);
        }
        __syncthreads();
    }
    float bb[4];
    *(float4*)bb = *(const float4*)&bia[ob + to * 4];

    if (which < 2) {
        float* out = ws + ((which == 0) ? QT_OFF : KT_OFF) + (size_t)b * HWN * CC;
        #pragma unroll
        for (int j2 = 0; j2 < 4; j2++) {
            const int n = nb + tn * 4 + j2;
            float4 vo = { acc[0][j2] + bb[0], acc[1][j2] + bb[1],
                          acc[2][j2] + bb[2], acc[3][j2] + bb[3] };
            *(float4*)&out[(size_t)n * CC + ob + to * 4] = vo;
        }
    }
    if (which >= 1) {
        const int o0  = ob + to * 4;
        const int b8h = b * NHD + (o0 >> 5);
        const int c0i = o0 & 31;
        unsigned short* bh_hi = (unsigned short*)(ws + ((which == 1) ? KBH_OFF : VBH_OFF));
        unsigned short* bh_lo = (unsigned short*)(ws + ((which == 1) ? KBL_OFF : VBL_OFF));
        if (which == 1) {
            // Kb[bh][j=n][c]: per n pack 4 c's (i2)
            #pragma unroll
            for (int j2 = 0; j2 < 4; j2++) {
                const int n = nb + tn * 4 + j2;
                unsigned int hh[2] = {0, 0}, ll[2] = {0, 0};
                #pragma unroll
                for (int i2 = 0; i2 < 4; i2++) {
                    float v = acc[i2][j2] + bb[i2];
                    unsigned short h = bf16_rne(v);
                    unsigned short l = bf16_rne(v - bf16_to_f(h));
                    hh[i2 >> 1] |= ((unsigned int)h) << ((i2 & 1) * 16);
                    ll[i2 >> 1] |= ((unsigned int)l) << ((i2 & 1) * 16);
                }
                const size_t idx = ((size_t)b8h * HWN + n) * CHD + c0i;
                *(uint2*)(bh_hi + idx) = make_uint2(hh[0], hh[1]);
                *(uint2*)(bh_lo + idx) = make_uint2(ll[0], ll[1]);
            }
        } else {
            // Vb[bh][c][j=n]: per c (i2) pack 4 n's (j2)
            #pragma unroll
            for (int i2 = 0; i2 < 4; i2++) {
                unsigned int hh[2] = {0, 0}, ll[2] = {0, 0};
                #pragma unroll
                for (int j2 = 0; j2 < 4; j2++) {
                    float v = acc[i2][j2] + bb[i2];
                    unsigned short h = bf16_rne(v);
                    unsigned short l = bf16_rne(v - bf16_to_f(h));
                    hh[j2 >> 1] |= ((unsigned int)h) << ((j2 & 1) * 16);
                    ll[j2 >> 1] |= ((unsigned int)l) << ((j2 & 1) * 16);
                }
                const size_t idx = ((size_t)b8h * CHD + c0i + i2) * HWN + nb + tn * 4;
                *(uint2*)(bh_hi + idx) = make_uint2(hh[0], hh[1]);
                *(uint2*)(bh_lo + idx) = make_uint2(ll[0], ll[1]);
            }
        }
    }
}

// ---------------------------------------------------------------------------
// Kernel B: softmax-bound constants (unchanged semantics).
// ---------------------------------------------------------------------------
__global__ __launch_bounds__(256) void bounds_kernel(
    const float* __restrict__ h_emb, const float* __restrict__ w_emb,
    float* __restrict__ ws)
{
    const float* Kt = ws + KT_OFF;
    float* bounds = ws + BD_OFF;
    __shared__ float red[256];
    const int t = threadIdx.x;
    const int bh = blockIdx.x;
    if (bh < 16) {
        const int b = bh >> 3, h = bh & 7;
        float mx = 0.f;
        for (int j = t; j < HWN; j += 256) {
            const float* kp = &Kt[((size_t)b * HWN + j) * CC + h * CHD];
            float s = 0.f;
            #pragma unroll
            for (int c = 0; c < CHD; c += 4) {
                float4 v = *(const float4*)&kp[c];
                s += v.x * v.x + v.y * v.y + v.z * v.z + v.w * v.w;
            }
            mx = fmaxf(mx, s);
        }
        red[t] = mx; __syncthreads();
        for (int s2 = 128; s2 > 0; s2 >>= 1) {
            if (t < s2) red[t] = fmaxf(red[t], red[t + s2]);
            __syncthreads();
        }
        if (t == 0) bounds[bh] = sqrtf(red[0]);
    } else {
        float mw = 0.f, mh = 0.f;
        if (t < 95) {
            float s = 0.f;
            for (int c = 0; c < CHD; c++) { float v = w_emb[t * CHD + c]; s += v * v; }
            mw = s;
            s = 0.f;
            for (int c = 0; c < CHD; c++) { float v = h_emb[t * CHD + c]; s += v * v; }
            mh = s;
        }
        red[t] = mw; __syncthreads();
        for (int s2 = 128; s2 > 0; s2 >>= 1) {
            if (t < s2) red[t] = fmaxf(red[t], red[t + s2]);
            __syncthreads();
        }
        const float rw = red[0]; __syncthreads();
        red[t] = mh; __syncthreads();
        for (int s2 = 128; s2 > 0; s2 >>= 1) {
            if (t < s2) red[t] = fmaxf(red[t], red[t + s2]);
            __syncthreads();
        }
        if (t == 0) bounds[16] = sqrtf(rw) + sqrtf(red[0]);
    }
}

// ---------------------------------------------------------------------------
// Kernel C: MFMA attention. grid (48 yi, 16 bh), block 128 (2 waves).
// wg = one image row of q (48 i = 3 i-subtiles per wave); wave w handles
// j image rows [w*24, w*24+24). Swapped QK^T (S^T) so P feeds PV's
// A-fragment directly. hi/lo bf16 splits everywhere (err ~2^-17).
// Bias: qw/qh tables via MFMA prologue; qw hoisted to regs (e0), qh 1 LDS
// read per chunk. Bound-based softmax (no online max), as v1.
// ---------------------------------------------------------------------------
__global__ __launch_bounds__(128) void attn_kernel(
    const float* __restrict__ h_emb, const float* __restrict__ w_emb,
    float* __restrict__ ws)
{
    const float* Qt = ws + QT_OFF;
    const float* bounds = ws + BD_OFF;
    const unsigned short* Kbh = (const unsigned short*)(ws + KBH_OFF);
    const unsigned short* Kbl = (const unsigned short*)(ws + KBL_OFF);
    const unsigned short* Vbh = (const unsigned short*)(ws + VBH_OFF);
    const unsigned short* Vbl = (const unsigned short*)(ws + VBL_OFF);
    float* OP = ws + OP_OFF;

    __shared__ float qw_lds[48 * 97];
    __shared__ float qh_lds[48 * 97];
    __shared__ float comb[64 * 28];
    __shared__ float ls[48];

    const int t = threadIdx.x;
    const int wv = t >> 6;          // wave 0/1
    const int lane = t & 63;
    const int il = lane & 15;       // i within subtile (and MFMA n-col)
    const int g  = lane >> 4;       // 4-row group
    const int yi = blockIdx.x;      // q image row
    const int bh = blockIdx.y;
    const int b = bh >> 3, h = bh & 7;
    const float c1 = 0.09016844005556021f;   // log2(e) / 16

    // ---- prologue: load Q rows (f32), norms, bf16 hi/lo fragments ----
    bf16x8 qhi[3], qlo[3];
    float c0[3];
    {
        const float bsum = bounds[bh] + bounds[16];
        #pragma unroll
        for (int isub = 0; isub < 3; isub++) {
            const float* qp = Qt + ((size_t)(b * HWN + yi * 48 + isub * 16 + il)) * CC
                              + h * CHD + g * 8;
            float qf[8];
            *(float4*)&qf[0] = *(const float4*)qp;
            *(float4*)&qf[4] = *(const float4*)(qp + 4);
            float qn = 0.f;
            #pragma unroll
            for (int e = 0; e < 8; e++) qn = fmaf(qf[e], qf[e], qn);
            qn += __shfl_xor(qn, 16);
            qn += __shfl_xor(qn, 32);
            c0[isub] = -sqrtf(qn) * bsum * c1;
            #pragma unroll
            for (int e = 0; e < 8; e++) {
                unsigned short hh = bf16_rne(qf[e]);
                qhi[isub][e] = (short)hh;
                qlo[isub][e] = (short)bf16_rne(qf[e] - bf16_to_f(hh));
            }
        }
    }

    // ---- prologue: qw (wave0) / qh (wave1) tables via MFMA ----
    {
        float* tbl = (wv == 0) ? qw_lds : qh_lds;
        const float* emb = (wv == 0) ? w_emb : h_emb;
        #pragma unroll
        for (int dsub = 0; dsub < 6; dsub++) {
            int d = dsub * 16 + il;
            if (d > 94) d = 94;           // clamp (col 95 never read)
            const float* ep = emb + (size_t)d * CHD + g * 8;
            float wf[8];
            *(float4*)&wf[0] = *(const float4*)ep;
            *(float4*)&wf[4] = *(const float4*)(ep + 4);
            bf16x8 whi, wlo;
            #pragma unroll
            for (int e = 0; e < 8; e++) {
                unsigned short hh = bf16_rne(wf[e]);
                whi[e] = (short)hh;
                wlo[e] = (short)bf16_rne(wf[e] - bf16_to_f(hh));
            }
            #pragma unroll
            for (int isub = 0; isub < 3; isub++) {
                f32x4 acc = {0.f, 0.f, 0.f, 0.f};
                acc = mfma32(qlo[isub], whi, acc);
                acc = mfma32(qhi[isub], wlo, acc);
                acc = mfma32(qhi[isub], whi, acc);
                #pragma unroll
                for (int r = 0; r < 4; r++)
                    tbl[(isub * 16 + 4 * g + r) * 97 + dsub * 16 + il] = acc[r];
            }
        }
    }
    __syncthreads();

    // ---- hoist qw bias into regs: e0[isub][jsub][r] (fixed across chunks) ----
    float e0[3][3][4];
    #pragma unroll
    for (int isub = 0; isub < 3; isub++) {
        const int xi = isub * 16 + il;
        #pragma unroll
        for (int jsub = 0; jsub < 3; jsub++)
            #pragma unroll
            for (int r = 0; r < 4; r++) {
                const int dx = (jsub * 16 + 4 * g + r) - xi + 47;
                e0[isub][jsub][r] = c0[isub] + c1 * qw_lds[xi * 97 + dx];
            }
    }

    // ---- main loop over this wave's j image rows ----
    f32x4 O[3][2] = {};
    float lac[3] = {0.f, 0.f, 0.f};

    for (int yj = wv * 24; yj < wv * 24 + 24; ++yj) {
        const int dy = yj - yi + 47;
        float qc[3];
        #pragma unroll
        for (int isub = 0; isub < 3; isub++)
            qc[isub] = c1 * qh_lds[(isub * 16 + il) * 97 + dy];

        bf16x4 phi[3][3], plo[3][3];   // [jsub][isub]
        #pragma unroll
        for (int jsub = 0; jsub < 3; jsub++) {
            const size_t kidx = ((size_t)bh * HWN + yj * 48 + jsub * 16 + il) * CHD + g * 8;
            const bf16x8 khi = *(const bf16x8*)(Kbh + kidx);
            const bf16x8 klo = *(const bf16x8*)(Kbl + kidx);
            #pragma unroll
            for (int isub = 0; isub < 3; isub++) {
                f32x4 acc = {0.f, 0.f, 0.f, 0.f};
                acc = mfma32(klo, qhi[isub], acc);
                acc = mfma32(khi, qlo[isub], acc);
                acc = mfma32(khi, qhi[isub], acc);
                float ps = 0.f;
                #pragma unroll
                for (int r = 0; r < 4; r++) {
                    const float arg = fmaf(acc[r], c1, e0[isub][jsub][r] + qc[isub]);
                    const float p = __builtin_amdgcn_exp2f(arg);
                    ps += p;
                    const unsigned short hh = bf16_rne(p);
                    phi[jsub][isub][r] = (short)hh;
                    plo[jsub][isub][r] = (short)bf16_rne(p - bf16_to_f(hh));
                }
                lac[isub] += ps;
            }
        }
        #pragma unroll
        for (int csub = 0; csub < 2; csub++) {
            #pragma unroll
            for (int jsub = 0; jsub < 3; jsub++) {
                const size_t vidx = ((size_t)bh * CHD + csub * 16 + il) * HWN
                                    + yj * 48 + jsub * 16 + g * 4;
                const bf16x4 vhi = *(const bf16x4*)(Vbh + vidx);
                const bf16x4 vlo = *(const bf16x4*)(Vbl + vidx);
                #pragma unroll
                for (int isub = 0; isub < 3; isub++) {
                    O[isub][csub] = mfma16(plo[jsub][isub], vhi, O[isub][csub]);
                    O[isub][csub] = mfma16(phi[jsub][isub], vlo, O[isub][csub]);
                    O[isub][csub] = mfma16(phi[jsub][isub], vhi, O[isub][csub]);
                }
            }
        }
    }

    // ---- combine the two waves' partials, normalize, store ----
    #pragma unroll
    for (int isub = 0; isub < 3; isub++) {
        lac[isub] += __shfl_xor(lac[isub], 16);
        lac[isub] += __shfl_xor(lac[isub], 32);
    }
    if (wv == 1) {
        float* cb = comb + lane * 28;
        #pragma unroll
        for (int isub = 0; isub < 3; isub++) {
            #pragma unroll
            for (int csub = 0; csub < 2; csub++)
                #pragma unroll
                for (int r = 0; r < 4; r++)
                    cb[(isub * 2 + csub) * 4 + r] = O[isub][csub][r];
            cb[24 + isub] = lac[isub];
        }
    }
    __syncthreads();
    if (wv == 0) {
        const float* cb = comb + lane * 28;
        #pragma unroll
        for (int isub = 0; isub < 3; isub++) {
            #pragma unroll
            for (int csub = 0; csub < 2; csub++)
                #pragma unroll
                for (int r = 0; r < 4; r++)
                    O[isub][csub][r] += cb[(isub * 2 + csub) * 4 + r];
            lac[isub] += cb[24 + isub];
        }
        if (lane < 16) {
            #pragma unroll
            for (int isub = 0; isub < 3; isub++)
                ls[isub * 16 + lane] = lac[isub];
        }
        float inv[3][4];
        #pragma unroll
        for (int isub = 0; isub < 3; isub++)
            #pragma unroll
            for (int r = 0; r < 4; r++)
                inv[isub][r] = 1.0f / ls[isub * 16 + 4 * g + r];
        #pragma unroll
        for (int isub = 0; isub < 3; isub++)
            #pragma unroll
            for (int csub = 0; csub < 2; csub++)
                #pragma unroll
                for (int r = 0; r < 4; r++)
                    OP[((size_t)bh * HWN + yi * 48 + isub * 16 + 4 * g + r) * CHD
                       + csub * 16 + il] = O[isub][csub][r] * inv[isub][r];
    }
}

// ---------------------------------------------------------------------------
// Kernel D: output projection. out[b][o][n] = sum_cg wo[o][cg]*A[b][cg][n]+bo
// A[b][cg][n] = OP[(b*8 + cg/32)*HWN + n][cg&31]  (pre-normalized).
// ---------------------------------------------------------------------------
__global__ __launch_bounds__(256) void out_kernel(
    const float* __restrict__ wo, const float* __restrict__ bo,
    const float* __restrict__ ws, float* __restrict__ out)
{
    const float* OP = ws + OP_OFF;
    const int nb = blockIdx.x * 64;
    const int ob = blockIdx.y * 64;
    const int b  = blockIdx.z;

    __shared__ float As[64][68];    // [cg_local][n_local]
    __shared__ float Wn[64][68];    // [o_local][cg_local]

    const int t = threadIdx.x;
    const int tn = t & 15, to = t >> 4;
    float acc[4][4] = {};

    for (int ci = 0; ci < 4; ci++) {           // 64-channel chunks
        for (int slot = t; slot < 1024; slot += 256) {
            const int n_l = slot >> 4, cq = slot & 15;
            const int h_l = ci * 2 + (cq >> 3), c_in = (cq & 7) * 4;
            const float4 u = *(const float4*)&OP[
                ((size_t)(b * NHD + h_l) * HWN + nb + n_l) * CHD + c_in];
            As[cq * 4 + 0][n_l] = u.x;
            As[cq * 4 + 1][n_l] = u.y;
            As[cq * 4 + 2][n_l] = u.z;
            As[cq * 4 + 3][n_l] = u.w;
        }
        {
            const int r = t >> 4, col = (t & 15) * 4;
            #pragma unroll
            for (int rr = 0; rr < 4; rr++) {
                const int row = r + rr * 16;
                *(float4*)&Wn[row][col] =
                    *(const float4*)&wo[(size_t)(ob + row) * CC + ci * 64 + col];
            }
        }
        __syncthreads();
        #pragma unroll 4
        for (int k = 0; k < 64; k++) {
            float av[4];
            #pragma unroll
            for (int i2 = 0; i2 < 4; i2++) av[i2] = Wn[to * 4 + i2][k];
            const float4 b4 = *(const float4*)&As[k][tn * 4];
            const float bv4[4] = {b4.x, b4.y, b4.z, b4.w};
            #pragma unroll
            for (int i2 = 0; i2 < 4; i2++)
                #pragma unroll
                for (int j2 = 0; j2 < 4; j2++)
                    acc[i2][j2] = fmaf(av[i2], bv4[j2], acc[i2][j2]);
        }
        __syncthreads();
    }
    #pragma unroll
    for (int i2 = 0; i2 < 4; i2++) {
        const int o = ob + to * 4 + i2;
        const float bb = bo[o];
        float4 vo = { acc[i2][0] + bb, acc[i2][1] + bb,
                      acc[i2][2] + bb, acc[i2][3] + bb };
        *(float4*)&out[((size_t)b * CC + o) * HWN + nb + tn * 4] = vo;
    }
}

// ---------------------------------------------------------------------------
extern "C" void kernel_launch(void* const* d_in, const int* in_sizes, int n_in,
                              void* d_out, int out_size, void* d_ws, size_t ws_size,
                              hipStream_t stream) {
    const float* x     = (const float*)d_in[0];
    const float* y     = (const float*)d_in[1];
    const float* wq    = (const float*)d_in[2];
    const float* bq    = (const float*)d_in[3];
    const float* wk    = (const float*)d_in[4];
    const float* bk    = (const float*)d_in[5];
    const float* wv    = (const float*)d_in[6];
    const float* bv    = (const float*)d_in[7];
    const float* wo    = (const float*)d_in[8];
    const float* bo    = (const float*)d_in[9];
    const float* h_emb = (const float*)d_in[10];
    const float* w_emb = (const float*)d_in[11];
    float* ws  = (float*)d_ws;
    float* out = (float*)d_out;

    dim3 gA(HWN / 64, CC / 64, 6);
    proj_kernel<<<gA, 256, 0, stream>>>(x, y, wq, bq, wk, bk, wv, bv, ws);
    bounds_kernel<<<17, 256, 0, stream>>>(h_emb, w_emb, ws);
    dim3 gC(48, 16);
    attn_kernel<<<gC, 128, 0, stream>>>(h_emb, w_emb, ws);
    dim3 gD(HWN / 64, CC / 64, 2);
    out_kernel<<<gD, 256, 0, stream>>>(wo, bo, ws, out);
}

// Round 8
// 195.478 us; speedup vs baseline: 2.4978x; 1.3120x over previous
//
#include <hip/hip_runtime.h>
#include <hip/hip_bf16.h>
#include <math.h>

// Problem constants (fixed by reference setup_inputs)
#define HWN 2304          // H*W
#define CC  256           // channels
#define NHD 8             // heads
#define CHD 32            // channels per head

// workspace layout (float offsets)
#define QT_OFF 0
#define KT_OFF (2 * HWN * CC)                   // f32 K (bounds kernel only)
#define OP_OFF (2 * KT_OFF)
#define KBH_OFF (OP_OFF + 16 * HWN * CHD)
#define KBL_OFF (KBH_OFF + (16 * HWN * CHD) / 2)
#define VB_OFF  (KBL_OFF + (16 * HWN * CHD) / 2)   // interleaved hi4/lo4 V
#define BD_OFF  (VB_OFF + 16 * HWN * CHD)

typedef __attribute__((ext_vector_type(8))) short bf16x8;
typedef __attribute__((ext_vector_type(4))) short bf16x4;
typedef __attribute__((ext_vector_type(4))) float f32x4;

__device__ inline unsigned short bf16_rne(float f) {
    unsigned int u = __float_as_uint(f);
    unsigned int r = u + 0x7FFFu + ((u >> 16) & 1u);
    return (unsigned short)(r >> 16);
}
__device__ inline float bf16_to_f(unsigned short h) {
    return __uint_as_float(((unsigned int)h) << 16);
}
__device__ inline bf16x4 bc4(int a, int b) {
    int2 t = make_int2(a, b);
    return __builtin_bit_cast(bf16x4, t);
}

__device__ inline f32x4 mfma32(bf16x8 a, bf16x8 b, f32x4 c) {
    return __builtin_amdgcn_mfma_f32_16x16x32_bf16(a, b, c, 0, 0, 0);
}
__device__ inline f32x4 mfma16(bf16x4 a, bf16x4 b, f32x4 c) {
#if __has_builtin(__builtin_amdgcn_mfma_f32_16x16x16bf16_1k)
    return __builtin_amdgcn_mfma_f32_16x16x16bf16_1k(a, b, c, 0, 0, 0);
#else
    f32x4 d;
    asm volatile("v_mfma_f32_16x16x16_bf16 %0, %1, %2, %3"
                 : "=v"(d) : "v"(a), "v"(b), "v"(c));
    return d;
#endif
}

// ---------------------------------------------------------------------------
// Kernel A: 1x1-conv projections. which: 0->Q(f32), 1->K(f32 + bf16 hi/lo),
// 2->V (bf16 interleaved hi4/lo4, transposed).
// Q/K f32 layout: [b][n][256]. Kb: [bh][j][32] bf16 (hi,lo separate).
// Vb: [bh][c][jg]{hi[4],lo[4]} shorts, jg = j/4.
// ---------------------------------------------------------------------------
__global__ __launch_bounds__(256) void proj_kernel(
    const float* __restrict__ x, const float* __restrict__ y,
    const float* __restrict__ wq, const float* __restrict__ bq,
    const float* __restrict__ wk, const float* __restrict__ bk,
    const float* __restrict__ wv, const float* __restrict__ bv,
    float* __restrict__ ws)
{
    const int nb = blockIdx.x * 64;
    const int ob = blockIdx.y * 64;
    const int z  = blockIdx.z;
    const int b = z / 3, which = z % 3;
    const float* in  = (which == 0) ? x : y;
    const float* W   = (which == 0) ? wq : (which == 1) ? wk : wv;
    const float* bia = (which == 0) ? bq : (which == 1) ? bk : bv;

    __shared__ float Xs[64][68];   // [c_local][n_local]
    __shared__ float Wn[64][68];   // [o_local][c_local]

    const int t  = threadIdx.x;
    const int tn = t & 15, to = t >> 4;
    float acc[4][4] = {};   // [o4][n4]

    for (int cc = 0; cc < CC; cc += 64) {
        const int r   = t >> 4;
        const int col = (t & 15) * 4;
        #pragma unroll
        for (int rr = 0; rr < 4; rr++) {
            const int row = r + rr * 16;
            *(float4*)&Xs[row][col] =
                *(const float4*)&in[((size_t)b * CC + cc + row) * HWN + nb + col];
            *(float4*)&Wn[row][col] =
                *(const float4*)&W[(size_t)(ob + row) * CC + cc + col];
        }
        __syncthreads();
        #pragma unroll 4
        for (int k = 0; k < 64; k++) {
            float av[4];
            #pragma unroll
            for (int i2 = 0; i2 < 4; i2++) av[i2] = Wn[to * 4 + i2][k];
            const float4 b4 = *(const float4*)&Xs[k][tn * 4];
            const float bv4[4] = {b4.x, b4.y, b4.z, b4.w};
            #pragma unroll
            for (int i2 = 0; i2 < 4; i2++)
                #pragma unroll
                for (int j2 = 0; j2 < 4; j2++)
                    acc[i2][j2] = fmaf(av[i2], bv4[j2], acc[i2][j2]);
        }
        __syncthreads();
    }
    float bb[4];
    *(float4*)bb = *(const float4*)&bia[ob + to * 4];

    if (which < 2) {
        float* out = ws + ((which == 0) ? QT_OFF : KT_OFF) + (size_t)b * HWN * CC;
        #pragma unroll
        for (int j2 = 0; j2 < 4; j2++) {
            const int n = nb + tn * 4 + j2;
            float4 vo = { acc[0][j2] + bb[0], acc[1][j2] + bb[1],
                          acc[2][j2] + bb[2], acc[3][j2] + bb[3] };
            *(float4*)&out[(size_t)n * CC + ob + to * 4] = vo;
        }
    }
    if (which == 1) {
        const int o0  = ob + to * 4;
        const int b8h = b * NHD + (o0 >> 5);
        const int c0i = o0 & 31;
        unsigned short* bh_hi = (unsigned short*)(ws + KBH_OFF);
        unsigned short* bh_lo = (unsigned short*)(ws + KBL_OFF);
        // Kb[bh][j=n][c]: per n pack 4 c's (i2)
        #pragma unroll
        for (int j2 = 0; j2 < 4; j2++) {
            const int n = nb + tn * 4 + j2;
            unsigned int hh[2] = {0, 0}, ll[2] = {0, 0};
            #pragma unroll
            for (int i2 = 0; i2 < 4; i2++) {
                float v = acc[i2][j2] + bb[i2];
                unsigned short h = bf16_rne(v);
                unsigned short l = bf16_rne(v - bf16_to_f(h));
                hh[i2 >> 1] |= ((unsigned int)h) << ((i2 & 1) * 16);
                ll[i2 >> 1] |= ((unsigned int)l) << ((i2 & 1) * 16);
            }
            const size_t idx = ((size_t)b8h * HWN + n) * CHD + c0i;
            *(uint2*)(bh_hi + idx) = make_uint2(hh[0], hh[1]);
            *(uint2*)(bh_lo + idx) = make_uint2(ll[0], ll[1]);
        }
    } else if (which == 2) {
        const int o0  = ob + to * 4;
        const int b8h = b * NHD + (o0 >> 5);
        const int c0i = o0 & 31;
        unsigned short* vb = (unsigned short*)(ws + VB_OFF);
        // Vb[bh][c][jg]{hi4,lo4}: per c (i2) pack 4 n's (j2)
        #pragma unroll
        for (int i2 = 0; i2 < 4; i2++) {
            unsigned int hh[2] = {0, 0}, ll[2] = {0, 0};
            #pragma unroll
            for (int j2 = 0; j2 < 4; j2++) {
                float v = acc[i2][j2] + bb[i2];
                unsigned short h = bf16_rne(v);
                unsigned short l = bf16_rne(v - bf16_to_f(h));
                hh[j2 >> 1] |= ((unsigned int)h) << ((j2 & 1) * 16);
                ll[j2 >> 1] |= ((unsigned int)l) << ((j2 & 1) * 16);
            }
            const size_t off = (((size_t)b8h * CHD + c0i + i2) * 576
                                + (nb >> 2) + tn) * 8;
            uint4 pk = { hh[0], hh[1], ll[0], ll[1] };
            *(uint4*)(vb + off) = pk;
        }
    }
}

// ---------------------------------------------------------------------------
// Kernel B: softmax-bound constants (unchanged).
// ---------------------------------------------------------------------------
__global__ __launch_bounds__(256) void bounds_kernel(
    const float* __restrict__ h_emb, const float* __restrict__ w_emb,
    float* __restrict__ ws)
{
    const float* Kt = ws + KT_OFF;
    float* bounds = ws + BD_OFF;
    __shared__ float red[256];
    const int t = threadIdx.x;
    const int bh = blockIdx.x;
    if (bh < 16) {
        const int b = bh >> 3, h = bh & 7;
        float mx = 0.f;
        for (int j = t; j < HWN; j += 256) {
            const float* kp = &Kt[((size_t)b * HWN + j) * CC + h * CHD];
            float s = 0.f;
            #pragma unroll
            for (int c = 0; c < CHD; c += 4) {
                float4 v = *(const float4*)&kp[c];
                s += v.x * v.x + v.y * v.y + v.z * v.z + v.w * v.w;
            }
            mx = fmaxf(mx, s);
        }
        red[t] = mx; __syncthreads();
        for (int s2 = 128; s2 > 0; s2 >>= 1) {
            if (t < s2) red[t] = fmaxf(red[t], red[t + s2]);
            __syncthreads();
        }
        if (t == 0) bounds[bh] = sqrtf(red[0]);
    } else {
        float mw = 0.f, mh = 0.f;
        if (t < 95) {
            float s = 0.f;
            for (int c = 0; c < CHD; c++) { float v = w_emb[t * CHD + c]; s += v * v; }
            mw = s;
            s = 0.f;
            for (int c = 0; c < CHD; c++) { float v = h_emb[t * CHD + c]; s += v * v; }
            mh = s;
        }
        red[t] = mw; __syncthreads();
        for (int s2 = 128; s2 > 0; s2 >>= 1) {
            if (t < s2) red[t] = fmaxf(red[t], red[t + s2]);
            __syncthreads();
        }
        const float rw = red[0]; __syncthreads();
        red[t] = mh; __syncthreads();
        for (int s2 = 128; s2 > 0; s2 >>= 1) {
            if (t < s2) red[t] = fmaxf(red[t], red[t + s2]);
            __syncthreads();
        }
        if (t == 0) bounds[16] = sqrtf(rw) + sqrtf(red[0]);
    }
}

// ---------------------------------------------------------------------------
// Kernel C: MFMA attention. grid (48,16) remapped XCD-aware; block 256
// (4 waves). wg = one image row of q (48 i); wave w handles yj rows
// [w*12, w*12+12). Swapped QK^T; truncation hi/lo split for P (perm-packed).
// Tables c1-premultiplied, stride 98 (bank-spread). 4-wave merge via LDS
// reuse of the dead qw-table region.
// ---------------------------------------------------------------------------
__global__ __launch_bounds__(256, 3) void attn_kernel(
    const float* __restrict__ h_emb, const float* __restrict__ w_emb,
    float* __restrict__ ws)
{
    const float* Qt = ws + QT_OFF;
    const float* bounds = ws + BD_OFF;
    const unsigned short* Kbh = (const unsigned short*)(ws + KBH_OFF);
    const unsigned short* Kbl = (const unsigned short*)(ws + KBL_OFF);
    const unsigned short* Vb  = (const unsigned short*)(ws + VB_OFF);
    float* OP = ws + OP_OFF;

    __shared__ float lds_a[5376];   // qw table (stride 98) -> merge buffer
    __shared__ float lds_b[4704];   // qh table (stride 98), c1-premultiplied

    const int t = threadIdx.x;
    const int wv = t >> 6;          // wave 0..3
    const int lane = t & 63;
    const int il = lane & 15;
    const int g  = lane >> 4;

    // XCD-aware swizzle: wgs with equal gid%8 land on the same XCD; give
    // each XCD two bh values so its K/V (~1.2 MB) stays L2-resident.
    const int gid = blockIdx.y * 48 + blockIdx.x;
    const int xcd = gid & 7;
    const int idx = gid >> 3;       // 0..95
    const int sub = idx / 48;
    const int yi  = idx - sub * 48; // q image row
    const int bh  = xcd * 2 + sub;
    const int b = bh >> 3, h = bh & 7;
    const float c1 = 0.09016844005556021f;   // log2(e) / 16

    // ---- prologue: Q fragments (all waves identical), c0 ----
    bf16x8 qhi[3], qlo[3];
    float c0[3];
    {
        const float bsum = bounds[bh] + bounds[16];
        #pragma unroll
        for (int isub = 0; isub < 3; isub++) {
            const float* qp = Qt + ((size_t)(b * HWN + yi * 48 + isub * 16 + il)) * CC
                              + h * CHD + g * 8;
            float qf[8];
            *(float4*)&qf[0] = *(const float4*)qp;
            *(float4*)&qf[4] = *(const float4*)(qp + 4);
            float qn = 0.f;
            #pragma unroll
            for (int e = 0; e < 8; e++) qn = fmaf(qf[e], qf[e], qn);
            qn += __shfl_xor(qn, 16);
            qn += __shfl_xor(qn, 32);
            c0[isub] = -sqrtf(qn) * bsum * c1;
            #pragma unroll
            for (int e = 0; e < 8; e++) {
                unsigned short hh = bf16_rne(qf[e]);
                qhi[isub][e] = (short)hh;
                qlo[isub][e] = (short)bf16_rne(qf[e] - bf16_to_f(hh));
            }
        }
    }

    // ---- prologue: bias tables via MFMA. waves 0,1 -> qw; 2,3 -> qh ----
    {
        float* tbl = (wv < 2) ? lds_a : lds_b;
        const float* emb = (wv < 2) ? w_emb : h_emb;
        const int ds0 = (wv & 1) * 3;
        #pragma unroll
        for (int dsub = ds0; dsub < ds0 + 3; dsub++) {
            int d = dsub * 16 + il;
            if (d > 94) d = 94;           // clamp (col 95 never read)
            const float* ep = emb + (size_t)d * CHD + g * 8;
            float wf[8];
            *(float4*)&wf[0] = *(const float4*)ep;
            *(float4*)&wf[4] = *(const float4*)(ep + 4);
            bf16x8 whi, wlo;
            #pragma unroll
            for (int e = 0; e < 8; e++) {
                unsigned short hh = bf16_rne(wf[e]);
                whi[e] = (short)hh;
                wlo[e] = (short)bf16_rne(wf[e] - bf16_to_f(hh));
            }
            #pragma unroll
            for (int isub = 0; isub < 3; isub++) {
                f32x4 acc = {0.f, 0.f, 0.f, 0.f};
                acc = mfma32(qlo[isub], whi, acc);
                acc = mfma32(qhi[isub], wlo, acc);
                acc = mfma32(qhi[isub], whi, acc);
                #pragma unroll
                for (int r = 0; r < 4; r++)
                    tbl[(isub * 16 + 4 * g + r) * 98 + dsub * 16 + il] = c1 * acc[r];
            }
        }
    }
    __syncthreads();

    // ---- hoist qw bias into regs: e0[isub][jsub][r] ----
    float e0[3][3][4];
    #pragma unroll
    for (int isub = 0; isub < 3; isub++) {
        const int xi = isub * 16 + il;
        #pragma unroll
        for (int jsub = 0; jsub < 3; jsub++)
            #pragma unroll
            for (int r = 0; r < 4; r++) {
                const int dx = (jsub * 16 + 4 * g + r) - xi + 47;
                e0[isub][jsub][r] = c0[isub] + lds_a[xi * 98 + dx];
            }
    }
    __syncthreads();   // lds_a (qw) dead after this; safe to reuse as comb

    // ---- main loop: this wave's 12 yj rows ----
    f32x4 O[3][2] = {};
    float lac[3] = {0.f, 0.f, 0.f};

    #pragma unroll 1
    for (int yj = wv * 12; yj < wv * 12 + 12; ++yj) {
        const int dy = yj - yi + 47;
        float qc[3];
        #pragma unroll
        for (int isub = 0; isub < 3; isub++)
            qc[isub] = lds_b[(isub * 16 + il) * 98 + dy];

        bf16x8 khi[3], klo[3];
        #pragma unroll
        for (int jsub = 0; jsub < 3; jsub++) {
            const size_t kidx = ((size_t)bh * HWN + yj * 48 + jsub * 16 + il) * CHD + g * 8;
            khi[jsub] = *(const bf16x8*)(Kbh + kidx);
            klo[jsub] = *(const bf16x8*)(Kbl + kidx);
        }
        #pragma unroll
        for (int jsub = 0; jsub < 3; jsub++) {
            int2 ph[3], pl[3];
            #pragma unroll
            for (int isub = 0; isub < 3; isub++) {
                f32x4 acc = {0.f, 0.f, 0.f, 0.f};
                acc = mfma32(klo[jsub], qhi[isub], acc);
                acc = mfma32(khi[jsub], qlo[isub], acc);
                acc = mfma32(khi[jsub], qhi[isub], acc);
                float p[4];
                unsigned u[4];
                #pragma unroll
                for (int r = 0; r < 4; r++) {
                    const float arg = fmaf(acc[r], c1, e0[isub][jsub][r]) + qc[isub];
                    p[r] = __builtin_amdgcn_exp2f(arg);
                    u[r] = __float_as_uint(p[r]);
                }
                lac[isub] += (p[0] + p[1]) + (p[2] + p[3]);
                // truncation split: hi = p & 0xffff0000, lo = p - hi (>=0).
                const unsigned h01 = __builtin_amdgcn_perm(u[1], u[0], 0x07060302u);
                const unsigned h23 = __builtin_amdgcn_perm(u[3], u[2], 0x07060302u);
                unsigned v[4];
                #pragma unroll
                for (int r = 0; r < 4; r++)
                    v[r] = __float_as_uint(p[r] - __uint_as_float(u[r] & 0xffff0000u));
                const unsigned l01 = __builtin_amdgcn_perm(v[1], v[0], 0x07060302u);
                const unsigned l23 = __builtin_amdgcn_perm(v[3], v[2], 0x07060302u);
                ph[isub] = make_int2((int)h01, (int)h23);
                pl[isub] = make_int2((int)l01, (int)l23);
            }
            #pragma unroll
            for (int csub = 0; csub < 2; csub++) {
                const size_t voff = (((size_t)bh * CHD + csub * 16 + il) * 576
                                     + yj * 12 + jsub * 4 + g) * 8;
                const int4 vv = *(const int4*)(Vb + voff);
                const bf16x4 vhi = bc4(vv.x, vv.y);
                const bf16x4 vlo = bc4(vv.z, vv.w);
                #pragma unroll
                for (int isub = 0; isub < 3; isub++) {
                    const bf16x4 pH = bc4(ph[isub].x, ph[isub].y);
                    const bf16x4 pL = bc4(pl[isub].x, pl[isub].y);
                    O[isub][csub] = mfma16(pL, vhi, O[isub][csub]);
                    O[isub][csub] = mfma16(pH, vlo, O[isub][csub]);
                    O[isub][csub] = mfma16(pH, vhi, O[isub][csub]);
                }
            }
        }
    }

    // ---- merge 4 waves, normalize, store ----
    #pragma unroll
    for (int isub = 0; isub < 3; isub++) {
        lac[isub] += __shfl_xor(lac[isub], 16);
        lac[isub] += __shfl_xor(lac[isub], 32);
    }
    if (wv > 0) {
        float* cb = lds_a + ((wv - 1) * 64 + lane) * 28;
        #pragma unroll
        for (int isub = 0; isub < 3; isub++)
            #pragma unroll
            for (int csub = 0; csub < 2; csub++)
                *(f32x4*)&cb[(isub * 2 + csub) * 4] = O[isub][csub];
        cb[24] = lac[0]; cb[25] = lac[1]; cb[26] = lac[2];
    }
    __syncthreads();
    if (wv == 0) {
        #pragma unroll 1
        for (int w = 1; w < 4; w++) {
            const float* cb = lds_a + ((w - 1) * 64 + lane) * 28;
            #pragma unroll
            for (int isub = 0; isub < 3; isub++) {
                #pragma unroll
                for (int csub = 0; csub < 2; csub++)
                    O[isub][csub] += *(const f32x4*)&cb[(isub * 2 + csub) * 4];
                lac[isub] += cb[24 + isub];
            }
        }
        float inv[3][4];
        #pragma unroll
        for (int isub = 0; isub < 3; isub++)
            #pragma unroll
            for (int r = 0; r < 4; r++)
                inv[isub][r] = 1.0f / __shfl(lac[isub], 4 * g + r);
        #pragma unroll
        for (int isub = 0; isub < 3; isub++)
            #pragma unroll
            for (int csub = 0; csub < 2; csub++)
                #pragma unroll
                for (int r = 0; r < 4; r++)
                    OP[((size_t)bh * HWN + yi * 48 + isub * 16 + 4 * g + r) * CHD
                       + csub * 16 + il] = O[isub][csub][r] * inv[isub][r];
    }
}

// ---------------------------------------------------------------------------
// Kernel D: output projection (unchanged).
// ---------------------------------------------------------------------------
__global__ __launch_bounds__(256) void out_kernel(
    const float* __restrict__ wo, const float* __restrict__ bo,
    const float* __restrict__ ws, float* __restrict__ out)
{
    const float* OP = ws + OP_OFF;
    const int nb = blockIdx.x * 64;
    const int ob = blockIdx.y * 64;
    const int b  = blockIdx.z;

    __shared__ float As[64][68];    // [cg_local][n_local]
    __shared__ float Wn[64][68];    // [o_local][cg_local]

    const int t = threadIdx.x;
    const int tn = t & 15, to = t >> 4;
    float acc[4][4] = {};

    for (int ci = 0; ci < 4; ci++) {           // 64-channel chunks
        for (int slot = t; slot < 1024; slot += 256) {
            const int n_l = slot >> 4, cq = slot & 15;
            const int h_l = ci * 2 + (cq >> 3), c_in = (cq & 7) * 4;
            const float4 u = *(const float4*)&OP[
                ((size_t)(b * NHD + h_l) * HWN + nb + n_l) * CHD + c_in];
            As[cq * 4 + 0][n_l] = u.x;
            As[cq * 4 + 1][n_l] = u.y;
            As[cq * 4 + 2][n_l] = u.z;
            As[cq * 4 + 3][n_l] = u.w;
        }
        {
            const int r = t >> 4, col = (t & 15) * 4;
            #pragma unroll
            for (int rr = 0; rr < 4; rr++) {
                const int row = r + rr * 16;
                *(float4*)&Wn[row][col] =
                    *(const float4*)&wo[(size_t)(ob + row) * CC + ci * 64 + col];
            }
        }
        __syncthreads();
        #pragma unroll 4
        for (int k = 0; k < 64; k++) {
            float av[4];
            #pragma unroll
            for (int i2 = 0; i2 < 4; i2++) av[i2] = Wn[to * 4 + i2][k];
            const float4 b4 = *(const float4*)&As[k][tn * 4];
            const float bv4[4] = {b4.x, b4.y, b4.z, b4.w};
            #pragma unroll
            for (int i2 = 0; i2 < 4; i2++)
                #pragma unroll
                for (int j2 = 0; j2 < 4; j2++)
                    acc[i2][j2] = fmaf(av[i2], bv4[j2], acc[i2][j2]);
        }
        __syncthreads();
    }
    #pragma unroll
    for (int i2 = 0; i2 < 4; i2++) {
        const int o = ob + to * 4 + i2;
        const float bb = bo[o];
        float4 vo = { acc[i2][0] + bb, acc[i2][1] + bb,
                      acc[i2][2] + bb, acc[i2][3] + bb };
        *(float4*)&out[((size_t)b * CC + o) * HWN + nb + tn * 4] = vo;
    }
}

// ---------------------------------------------------------------------------
extern "C" void kernel_launch(void* const* d_in, const int* in_sizes, int n_in,
                              void* d_out, int out_size, void* d_ws, size_t ws_size,
                              hipStream_t stream) {
    const float* x     = (const float*)d_in[0];
    const float* y     = (const float*)d_in[1];
    const float* wq    = (const float*)d_in[2];
    const float* bq    = (const float*)d_in[3];
    const float* wk    = (const float*)d_in[4];
    const float* bk    = (const float*)d_in[5];
    const float* wv    = (const float*)d_in[6];
    const float* bv    = (const float*)d_in[7];
    const float* wo    = (const float*)d_in[8];
    const float* bo    = (const float*)d_in[9];
    const float* h_emb = (const float*)d_in[10];
    const float* w_emb = (const float*)d_in[11];
    float* ws  = (float*)d_ws;
    float* out = (float*)d_out;

    dim3 gA(HWN / 64, CC / 64, 6);
    proj_kernel<<<gA, 256, 0, stream>>>(x, y, wq, bq, wk, bk, wv, bv, ws);
    bounds_kernel<<<17, 256, 0, stream>>>(h_emb, w_emb, ws);
    dim3 gC(48, 16);
    attn_kernel<<<gC, 256, 0, stream>>>(h_emb, w_emb, ws);
    dim3 gD(HWN / 64, CC / 64, 2);
    out_kernel<<<gD, 256, 0, stream>>>(wo, bo, ws, out);
}

// Round 10
// 194.469 us; speedup vs baseline: 2.5108x; 1.0052x over previous
//
#include <hip/hip_runtime.h>
#include <hip/hip_bf16.h>
#include <math.h>

// Problem constants (fixed by reference setup_inputs)
#define HWN 2304          // H*W
#define CC  256           // channels
#define NHD 8             // heads
#define CHD 32            // channels per head

// ---- workspace layout: u16-element offsets ----
#define SZT (2 * HWN * CC)          // 1179648 u16 per standard array
#define XTH 0                       // x^T hi  [b][n][256] bf16
#define XTL (1 * SZT)               // x^T lo
#define YTH (2 * SZT)               // y^T hi
#define YTL (3 * SZT)               // y^T lo
#define QBH (4 * SZT)               // Q hi  [bh][n][32]
#define QBL (5 * SZT)
#define KBH (6 * SZT)               // K hi  [bh][j][32]
#define KBL (7 * SZT)
#define VBI (8 * SZT)               // V interleaved {hi4,lo4} [bh][c][j/4][8], 2*SZT
#define OBH (10 * SZT)              // attn-out hi [bh][n][32]
#define OBL (11 * SZT)
#define WB  (12 * SZT)              // 4 weights x (65536 hi + 65536 lo): wq,wk,wv,wo
#define BD16 (WB + 8 * 65536)       // f32 bounds[17] region (u16 offset)

typedef __attribute__((ext_vector_type(8))) short bf16x8;
typedef __attribute__((ext_vector_type(4))) short bf16x4;
typedef __attribute__((ext_vector_type(4))) float f32x4;

__device__ inline unsigned short bf16_rne(float f) {
    unsigned int u = __float_as_uint(f);
    unsigned int r = u + 0x7FFFu + ((u >> 16) & 1u);
    return (unsigned short)(r >> 16);
}
__device__ inline float bf16_to_f(unsigned short h) {
    return __uint_as_float(((unsigned int)h) << 16);
}
__device__ inline bf16x4 bc4(int a, int b) {
    int2 t = make_int2(a, b);
    return __builtin_bit_cast(bf16x4, t);
}
// split-pack two floats: returns hi-pair and lo-pair u32s
__device__ inline void split2(float a, float b, unsigned& hp, unsigned& lp) {
    unsigned short ha = bf16_rne(a), hb = bf16_rne(b);
    hp = (unsigned)ha | ((unsigned)hb << 16);
    lp = (unsigned)bf16_rne(a - bf16_to_f(ha))
       | ((unsigned)bf16_rne(b - bf16_to_f(hb)) << 16);
}

__device__ inline f32x4 mfma32(bf16x8 a, bf16x8 b, f32x4 c) {
    return __builtin_amdgcn_mfma_f32_16x16x32_bf16(a, b, c, 0, 0, 0);
}
__device__ inline f32x4 mfma16(bf16x4 a, bf16x4 b, f32x4 c) {
#if __has_builtin(__builtin_amdgcn_mfma_f32_16x16x16bf16_1k)
    return __builtin_amdgcn_mfma_f32_16x16x16bf16_1k(a, b, c, 0, 0, 0);
#else
    f32x4 d;
    asm volatile("v_mfma_f32_16x16x16_bf16 %0, %1, %2, %3"
                 : "=v"(d) : "v"(a), "v"(b), "v"(c));
    return d;
#endif
}

// ---------------------------------------------------------------------------
// Kernel T: prep. blocks 0..575: transpose+split x,y 64x64 tiles into
// xt/yt hi/lo [b][n][256] bf16. blocks 576..639: split wq,wk,wv,wo into
// bf16 hi/lo (natural [o][c] layout).
// ---------------------------------------------------------------------------
__global__ __launch_bounds__(256) void prep_kernel(
    const float* __restrict__ x, const float* __restrict__ y,
    const float* __restrict__ wq, const float* __restrict__ wk,
    const float* __restrict__ wv, const float* __restrict__ wo,
    unsigned short* __restrict__ u16)
{
    const int t = threadIdx.x;
    const int bid = blockIdx.x;
    if (bid < 576) {
        const int z = bid / 144;
        const int r2 = bid - z * 144;
        const int ct = r2 / 36, nt = r2 - ct * 36;
        const int inp = z >> 1, b = z & 1;
        const float* in = inp ? y : x;
        unsigned short* oh = u16 + (inp ? YTH : XTH);
        unsigned short* ol = u16 + (inp ? YTL : XTL);
        const int nb = nt * 64, cb = ct * 64;
        __shared__ float Xs[64][68];
        {
            const int row = t >> 4, col = (t & 15) * 4;
            #pragma unroll
            for (int rr = 0; rr < 4; rr++) {
                const int c = row + rr * 16;
                *(float4*)&Xs[c][col] =
                    *(const float4*)&in[((size_t)b * CC + cb + c) * HWN + nb + col];
            }
        }
        __syncthreads();
        const int n4 = t >> 2, cg = (t & 3) * 16;
        unsigned hh[8], ll[8];
        #pragma unroll
        for (int e2 = 0; e2 < 8; e2++)
            split2(Xs[cg + 2 * e2][n4], Xs[cg + 2 * e2 + 1][n4], hh[e2], ll[e2]);
        const size_t o0 = ((size_t)b * HWN + nb + n4) * CC + cb + cg;
        *(uint4*)(oh + o0)     = make_uint4(hh[0], hh[1], hh[2], hh[3]);
        *(uint4*)(oh + o0 + 8) = make_uint4(hh[4], hh[5], hh[6], hh[7]);
        *(uint4*)(ol + o0)     = make_uint4(ll[0], ll[1], ll[2], ll[3]);
        *(uint4*)(ol + o0 + 8) = make_uint4(ll[4], ll[5], ll[6], ll[7]);
    } else {
        const int bid2 = bid - 576;
        const int w = bid2 >> 4, seg = bid2 & 15;
        const float* W = (w == 0) ? wq : (w == 1) ? wk : (w == 2) ? wv : wo;
        unsigned short* wh = u16 + WB + w * 131072;
        unsigned short* wl = wh + 65536;
        const int i0 = seg * 4096 + t * 16;
        float v[16];
        #pragma unroll
        for (int j = 0; j < 4; j++)
            *(float4*)&v[j * 4] = *(const float4*)&W[i0 + j * 4];
        unsigned hh[8], ll[8];
        #pragma unroll
        for (int e2 = 0; e2 < 8; e2++)
            split2(v[2 * e2], v[2 * e2 + 1], hh[e2], ll[e2]);
        *(uint4*)(wh + i0)     = make_uint4(hh[0], hh[1], hh[2], hh[3]);
        *(uint4*)(wh + i0 + 8) = make_uint4(hh[4], hh[5], hh[6], hh[7]);
        *(uint4*)(wl + i0)     = make_uint4(ll[0], ll[1], ll[2], ll[3]);
        *(uint4*)(wl + i0 + 8) = make_uint4(ll[4], ll[5], ll[6], ll[7]);
    }
}

// ---------------------------------------------------------------------------
// Kernel P: MFMA projections. grid (36 nt, 4 ot, 6 z={b,which}), block 256
// (4 waves, wave w4 = o-subtile of 16). Tile 64o x 64n, K=256 in chunks of 32.
// No LDS: both operands pre-split bf16, k-contiguous; L1/L2 serve reuse.
// Q/K: D[o][n] (A=W,B=X). V: D[j][c] (A=X,B=W) -> interleaved Vb layout.
// ---------------------------------------------------------------------------
__global__ __launch_bounds__(256) void proj_kernel(
    const float* __restrict__ bq, const float* __restrict__ bk,
    const float* __restrict__ bv, unsigned short* __restrict__ u16)
{
    const int nt = blockIdx.x, ot = blockIdx.y, z = blockIdx.z;
    const int b = z / 3, which = z - b * 3;
    const unsigned short* Xh = u16 + (which == 0 ? XTH : YTH);
    const unsigned short* Xl = u16 + (which == 0 ? XTL : YTL);
    const unsigned short* Wh = u16 + WB + which * 131072;
    const unsigned short* Wl = Wh + 65536;
    const float* bias = (which == 0) ? bq : (which == 1) ? bk : bv;
    const int t = threadIdx.x, w4 = t >> 6, lane = t & 63;
    const int il = lane & 15, g = lane >> 4;
    const int nb = nt * 64, ob = ot * 64 + w4 * 16;

    f32x4 acc[4] = {};
    const size_t xbase = ((size_t)b * HWN + nb + il) * CC;
    const size_t wbase = (size_t)(ob + il) * CC;
    for (int kc = 0; kc < 256; kc += 32) {
        const size_t wi = wbase + kc + g * 8;
        const bf16x8 whi = *(const bf16x8*)(Wh + wi);
        const bf16x8 wlo = *(const bf16x8*)(Wl + wi);
        #pragma unroll
        for (int ns = 0; ns < 4; ns++) {
            const size_t xi = xbase + (size_t)ns * 16 * CC + kc + g * 8;
            const bf16x8 xhi = *(const bf16x8*)(Xh + xi);
            const bf16x8 xlo = *(const bf16x8*)(Xl + xi);
            if (which != 2)
                acc[ns] = mfma32(whi, xhi, mfma32(whi, xlo, mfma32(wlo, xhi, acc[ns])));
            else
                acc[ns] = mfma32(xhi, whi, mfma32(xlo, whi, mfma32(xhi, wlo, acc[ns])));
        }
    }
    const int bh = b * NHD + ot * 2 + (w4 >> 1);
    if (which != 2) {
        // lane holds out[o = ob+4g+r][n = nb+ns*16+il]
        const int c0 = (w4 & 1) * 16 + 4 * g;
        float bb4[4];
        *(float4*)bb4 = *(const float4*)&bias[ob + 4 * g];
        unsigned short* Oh = u16 + (which == 0 ? QBH : KBH);
        unsigned short* Ol = u16 + (which == 0 ? QBL : KBL);
        #pragma unroll
        for (int ns = 0; ns < 4; ns++) {
            const int n = nb + ns * 16 + il;
            unsigned hh[2], ll[2];
            #pragma unroll
            for (int r = 0; r < 2; r++)
                split2(acc[ns][2 * r] + bb4[2 * r], acc[ns][2 * r + 1] + bb4[2 * r + 1],
                       hh[r], ll[r]);
            const size_t oi = ((size_t)bh * HWN + n) * CHD + c0;
            *(uint2*)(Oh + oi) = make_uint2(hh[0], hh[1]);
            *(uint2*)(Ol + oi) = make_uint2(ll[0], ll[1]);
        }
    } else {
        // lane holds out[j = nb+ns*16+4g+r][c = (w4&1)*16+il]
        const int c = (w4 & 1) * 16 + il;
        const float bb = bias[ot * 64 + w4 * 16 + il];
        unsigned short* vb = u16 + VBI;
        #pragma unroll
        for (int ns = 0; ns < 4; ns++) {
            const int jg = nb / 4 + ns * 4 + g;
            unsigned hh[2], ll[2];
            #pragma unroll
            for (int r = 0; r < 2; r++)
                split2(acc[ns][2 * r] + bb, acc[ns][2 * r + 1] + bb, hh[r], ll[r]);
            *(uint4*)(vb + (((size_t)bh * CHD + c) * 576 + jg) * 8) =
                make_uint4(hh[0], hh[1], ll[0], ll[1]);
        }
    }
}

// ---------------------------------------------------------------------------
// Kernel B: softmax-bound constants. K-norms from Kb hi+lo reconstruction.
// ---------------------------------------------------------------------------
__global__ __launch_bounds__(256) void bounds_kernel(
    const float* __restrict__ h_emb, const float* __restrict__ w_emb,
    unsigned short* __restrict__ u16)
{
    float* bounds = (float*)(u16 + BD16);
    __shared__ float red[256];
    const int t = threadIdx.x;
    const int bh = blockIdx.x;
    if (bh < 16) {
        const unsigned short* kh = u16 + KBH;
        const unsigned short* kl = u16 + KBL;
        float mx = 0.f;
        for (int j = t; j < HWN; j += 256) {
            const size_t base = ((size_t)bh * HWN + j) * CHD;
            float s = 0.f;
            #pragma unroll
            for (int q2 = 0; q2 < 4; q2++) {
                const uint4 H = *(const uint4*)(kh + base + q2 * 8);
                const uint4 L = *(const uint4*)(kl + base + q2 * 8);
                const unsigned hw[4] = {H.x, H.y, H.z, H.w};
                const unsigned lw[4] = {L.x, L.y, L.z, L.w};
                #pragma unroll
                for (int m = 0; m < 4; m++) {
                    const float v0 = bf16_to_f((unsigned short)(hw[m] & 0xffffu))
                                   + bf16_to_f((unsigned short)(lw[m] & 0xffffu));
                    const float v1 = bf16_to_f((unsigned short)(hw[m] >> 16))
                                   + bf16_to_f((unsigned short)(lw[m] >> 16));
                    s = fmaf(v0, v0, s);
                    s = fmaf(v1, v1, s);
                }
            }
            mx = fmaxf(mx, s);
        }
        red[t] = mx; __syncthreads();
        for (int s2 = 128; s2 > 0; s2 >>= 1) {
            if (t < s2) red[t] = fmaxf(red[t], red[t + s2]);
            __syncthreads();
        }
        if (t == 0) bounds[bh] = sqrtf(red[0]);
    } else {
        float mw = 0.f, mh = 0.f;
        if (t < 95) {
            float s = 0.f;
            for (int c = 0; c < CHD; c++) { float v = w_emb[t * CHD + c]; s += v * v; }
            mw = s;
            s = 0.f;
            for (int c = 0; c < CHD; c++) { float v = h_emb[t * CHD + c]; s += v * v; }
            mh = s;
        }
        red[t] = mw; __syncthreads();
        for (int s2 = 128; s2 > 0; s2 >>= 1) {
            if (t < s2) red[t] = fmaxf(red[t], red[t + s2]);
            __syncthreads();
        }
        const float rw = red[0]; __syncthreads();
        red[t] = mh; __syncthreads();
        for (int s2 = 128; s2 > 0; s2 >>= 1) {
            if (t < s2) red[t] = fmaxf(red[t], red[t + s2]);
            __syncthreads();
        }
        if (t == 0) bounds[16] = sqrtf(rw) + sqrtf(red[0]);
    }
}

// ---------------------------------------------------------------------------
// Kernel C: MFMA attention (core unchanged from verified round-8 kernel).
// Changes: Q frags loaded directly from Qb hi/lo; output written as bf16
// hi/lo (OBH/OBL) for the MFMA out-projection.
// ---------------------------------------------------------------------------
__global__ __launch_bounds__(256, 3) void attn_kernel(
    const float* __restrict__ h_emb, const float* __restrict__ w_emb,
    unsigned short* __restrict__ u16)
{
    const float* bounds = (const float*)(u16 + BD16);
    const unsigned short* Kbh = u16 + KBH;
    const unsigned short* Kbl = u16 + KBL;
    const unsigned short* Vb  = u16 + VBI;

    __shared__ float lds_a[5376];   // qw table (stride 98) -> merge buffer
    __shared__ float lds_b[4704];   // qh table (stride 98), c1-premultiplied

    const int t = threadIdx.x;
    const int wv = t >> 6;          // wave 0..3
    const int lane = t & 63;
    const int il = lane & 15;
    const int g  = lane >> 4;

    const int gid = blockIdx.y * 48 + blockIdx.x;
    const int xcd = gid & 7;
    const int idx = gid >> 3;       // 0..95
    const int sub = idx / 48;
    const int yi  = idx - sub * 48; // q image row
    const int bh  = xcd * 2 + sub;
    const float c1 = 0.09016844005556021f;   // log2(e) / 16

    // ---- prologue: Q fragments direct from Qb; c0 from reconstruction ----
    bf16x8 qhi[3], qlo[3];
    float c0[3];
    {
        const unsigned short* Qh = u16 + QBH;
        const unsigned short* Ql = u16 + QBL;
        const float bsum = bounds[bh] + bounds[16];
        #pragma unroll
        for (int isub = 0; isub < 3; isub++) {
            const size_t qi = ((size_t)bh * HWN + yi * 48 + isub * 16 + il) * CHD + g * 8;
            qhi[isub] = *(const bf16x8*)(Qh + qi);
            qlo[isub] = *(const bf16x8*)(Ql + qi);
            float qn = 0.f;
            #pragma unroll
            for (int e = 0; e < 8; e++) {
                const float v = bf16_to_f((unsigned short)qhi[isub][e])
                              + bf16_to_f((unsigned short)qlo[isub][e]);
                qn = fmaf(v, v, qn);
            }
            qn += __shfl_xor(qn, 16);
            qn += __shfl_xor(qn, 32);
            c0[isub] = -sqrtf(qn) * bsum * c1;
        }
    }

    // ---- prologue: bias tables via MFMA. waves 0,1 -> qw; 2,3 -> qh ----
    {
        float* tbl = (wv < 2) ? lds_a : lds_b;
        const float* emb = (wv < 2) ? w_emb : h_emb;
        const int ds0 = (wv & 1) * 3;
        #pragma unroll
        for (int dsub = ds0; dsub < ds0 + 3; dsub++) {
            int d = dsub * 16 + il;
            if (d > 94) d = 94;           // clamp (col 95 never read)
            const float* ep = emb + (size_t)d * CHD + g * 8;
            float wf[8];
            *(float4*)&wf[0] = *(const float4*)ep;
            *(float4*)&wf[4] = *(const float4*)(ep + 4);
            bf16x8 whi, wlo;
            #pragma unroll
            for (int e = 0; e < 8; e++) {
                unsigned short hhw = bf16_rne(wf[e]);
                whi[e] = (short)hhw;
                wlo[e] = (short)bf16_rne(wf[e] - bf16_to_f(hhw));
            }
            #pragma unroll
            for (int isub = 0; isub < 3; isub++) {
                f32x4 acc = {0.f, 0.f, 0.f, 0.f};
                acc = mfma32(qlo[isub], whi, acc);
                acc = mfma32(qhi[isub], wlo, acc);
                acc = mfma32(qhi[isub], whi, acc);
                #pragma unroll
                for (int r = 0; r < 4; r++)
                    tbl[(isub * 16 + 4 * g + r) * 98 + dsub * 16 + il] = c1 * acc[r];
            }
        }
    }
    __syncthreads();

    // ---- hoist qw bias into regs ----
    float e0[3][3][4];
    #pragma unroll
    for (int isub = 0; isub < 3; isub++) {
        const int xi = isub * 16 + il;
        #pragma unroll
        for (int jsub = 0; jsub < 3; jsub++)
            #pragma unroll
            for (int r = 0; r < 4; r++) {
                const int dx = (jsub * 16 + 4 * g + r) - xi + 47;
                e0[isub][jsub][r] = c0[isub] + lds_a[xi * 98 + dx];
            }
    }
    __syncthreads();   // lds_a dead; reused as merge buffer

    // ---- main loop: this wave's 12 yj rows ----
    f32x4 O[3][2] = {};
    float lac[3] = {0.f, 0.f, 0.f};

    #pragma unroll 1
    for (int yj = wv * 12; yj < wv * 12 + 12; ++yj) {
        const int dy = yj - yi + 47;
        float qc[3];
        #pragma unroll
        for (int isub = 0; isub < 3; isub++)
            qc[isub] = lds_b[(isub * 16 + il) * 98 + dy];

        bf16x8 khi[3], klo[3];
        #pragma unroll
        for (int jsub = 0; jsub < 3; jsub++) {
            const size_t kidx = ((size_t)bh * HWN + yj * 48 + jsub * 16 + il) * CHD + g * 8;
            khi[jsub] = *(const bf16x8*)(Kbh + kidx);
            klo[jsub] = *(const bf16x8*)(Kbl + kidx);
        }
        #pragma unroll
        for (int jsub = 0; jsub < 3; jsub++) {
            int2 ph[3], pl[3];
            #pragma unroll
            for (int isub = 0; isub < 3; isub++) {
                f32x4 acc = {0.f, 0.f, 0.f, 0.f};
                acc = mfma32(klo[jsub], qhi[isub], acc);
                acc = mfma32(khi[jsub], qlo[isub], acc);
                acc = mfma32(khi[jsub], qhi[isub], acc);
                float p[4];
                unsigned u[4];
                #pragma unroll
                for (int r = 0; r < 4; r++) {
                    const float arg = fmaf(acc[r], c1, e0[isub][jsub][r]) + qc[isub];
                    p[r] = __builtin_amdgcn_exp2f(arg);
                    u[r] = __float_as_uint(p[r]);
                }
                lac[isub] += (p[0] + p[1]) + (p[2] + p[3]);
                const unsigned h01 = __builtin_amdgcn_perm(u[1], u[0], 0x07060302u);
                const unsigned h23 = __builtin_amdgcn_perm(u[3], u[2], 0x07060302u);
                unsigned v[4];
                #pragma unroll
                for (int r = 0; r < 4; r++)
                    v[r] = __float_as_uint(p[r] - __uint_as_float(u[r] & 0xffff0000u));
                const unsigned l01 = __builtin_amdgcn_perm(v[1], v[0], 0x07060302u);
                const unsigned l23 = __builtin_amdgcn_perm(v[3], v[2], 0x07060302u);
                ph[isub] = make_int2((int)h01, (int)h23);
                pl[isub] = make_int2((int)l01, (int)l23);
            }
            #pragma unroll
            for (int csub = 0; csub < 2; csub++) {
                const size_t voff = (((size_t)bh * CHD + csub * 16 + il) * 576
                                     + yj * 12 + jsub * 4 + g) * 8;
                const int4 vv = *(const int4*)(Vb + voff);
                const bf16x4 vhi = bc4(vv.x, vv.y);
                const bf16x4 vlo = bc4(vv.z, vv.w);
                #pragma unroll
                for (int isub = 0; isub < 3; isub++) {
                    const bf16x4 pH = bc4(ph[isub].x, ph[isub].y);
                    const bf16x4 pL = bc4(pl[isub].x, pl[isub].y);
                    O[isub][csub] = mfma16(pL, vhi, O[isub][csub]);
                    O[isub][csub] = mfma16(pH, vlo, O[isub][csub]);
                    O[isub][csub] = mfma16(pH, vhi, O[isub][csub]);
                }
            }
        }
    }

    // ---- merge 4 waves, normalize, store bf16 hi/lo ----
    #pragma unroll
    for (int isub = 0; isub < 3; isub++) {
        lac[isub] += __shfl_xor(lac[isub], 16);
        lac[isub] += __shfl_xor(lac[isub], 32);
    }
    if (wv > 0) {
        float* cb = lds_a + ((wv - 1) * 64 + lane) * 28;
        #pragma unroll
        for (int isub = 0; isub < 3; isub++) {
            #pragma unroll
            for (int csub = 0; csub < 2; csub++)
                *(f32x4*)&cb[(isub * 2 + csub) * 4] = O[isub][csub];
            cb[24 + isub] = lac[isub];
        }
    }
    __syncthreads();
    if (wv == 0) {
        #pragma unroll 1
        for (int w = 1; w < 4; w++) {
            const float* cb = lds_a + ((w - 1) * 64 + lane) * 28;
            #pragma unroll
            for (int isub = 0; isub < 3; isub++) {
                #pragma unroll
                for (int csub = 0; csub < 2; csub++)
                    O[isub][csub] += *(const f32x4*)&cb[(isub * 2 + csub) * 4];
                lac[isub] += cb[24 + isub];
            }
        }
        float inv[3][4];
        #pragma unroll
        for (int isub = 0; isub < 3; isub++)
            #pragma unroll
            for (int r = 0; r < 4; r++)
                inv[isub][r] = 1.0f / __shfl(lac[isub], 4 * g + r);
        unsigned short* Obh = u16 + OBH;
        unsigned short* Obl = u16 + OBL;
        #pragma unroll
        for (int isub = 0; isub < 3; isub++)
            #pragma unroll
            for (int csub = 0; csub < 2; csub++)
                #pragma unroll
                for (int r = 0; r < 4; r++) {
                    const float v = O[isub][csub][r] * inv[isub][r];
                    const unsigned short hv = bf16_rne(v);
                    const size_t oi =
                        ((size_t)bh * HWN + yi * 48 + isub * 16 + 4 * g + r) * CHD
                        + csub * 16 + il;
                    Obh[oi] = hv;
                    Obl[oi] = bf16_rne(v - bf16_to_f(hv));
                }
    }
}

// ---------------------------------------------------------------------------
// Kernel O: MFMA output projection. grid (72 nt, 4 ot, 2 b), block 256
// (4 waves, 16o each), tile 64o x 32n. A=wo (pre-split), B=attn-out (hi/lo).
// ---------------------------------------------------------------------------
__global__ __launch_bounds__(256) void out_kernel(
    const float* __restrict__ bo, const unsigned short* __restrict__ u16,
    float* __restrict__ out)
{
    const int nt = blockIdx.x, ot = blockIdx.y, b = blockIdx.z;
    const int t = threadIdx.x, w4 = t >> 6, lane = t & 63;
    const int il = lane & 15, g = lane >> 4;
    const int nb = nt * 32, ob = ot * 64 + w4 * 16;
    const unsigned short* Oh = u16 + OBH;
    const unsigned short* Ol = u16 + OBL;
    const unsigned short* Wh = u16 + WB + 3 * 131072;
    const unsigned short* Wl = Wh + 65536;
    f32x4 acc[2] = {};
    #pragma unroll
    for (int h = 0; h < 8; h++) {
        const size_t wi = (size_t)(ob + il) * CC + h * 32 + g * 8;
        const bf16x8 whi = *(const bf16x8*)(Wh + wi);
        const bf16x8 wlo = *(const bf16x8*)(Wl + wi);
        #pragma unroll
        for (int ns = 0; ns < 2; ns++) {
            const size_t xi = ((size_t)(b * NHD + h) * HWN + nb + ns * 16 + il) * CHD + g * 8;
            const bf16x8 xhi = *(const bf16x8*)(Oh + xi);
            const bf16x8 xlo = *(const bf16x8*)(Ol + xi);
            acc[ns] = mfma32(whi, xhi, mfma32(whi, xlo, mfma32(wlo, xhi, acc[ns])));
        }
    }
    float bb4[4];
    *(float4*)bb4 = *(const float4*)&bo[ob + 4 * g];
    #pragma unroll
    for (int ns = 0; ns < 2; ns++)
        #pragma unroll
        for (int r = 0; r < 4; r++)
            out[((size_t)(b * CC + ob + 4 * g + r)) * HWN + nb + ns * 16 + il]
                = acc[ns][r] + bb4[r];
}

// ---------------------------------------------------------------------------
extern "C" void kernel_launch(void* const* d_in, const int* in_sizes, int n_in,
                              void* d_out, int out_size, void* d_ws, size_t ws_size,
                              hipStream_t stream) {
    const float* x     = (const float*)d_in[0];
    const float* y     = (const float*)d_in[1];
    const float* wq    = (const float*)d_in[2];
    const float* bq    = (const float*)d_in[3];
    const float* wk    = (const float*)d_in[4];
    const float* bk    = (const float*)d_in[5];
    const float* wvp   = (const float*)d_in[6];
    const float* bv    = (const float*)d_in[7];
    const float* wo    = (const float*)d_in[8];
    const float* bo    = (const float*)d_in[9];
    const float* h_emb = (const float*)d_in[10];
    const float* w_emb = (const float*)d_in[11];
    unsigned short* u16 = (unsigned short*)d_ws;
    float* out = (float*)d_out;

    prep_kernel<<<640, 256, 0, stream>>>(x, y, wq, wk, wvp, wo, u16);
    proj_kernel<<<dim3(36, 4, 6), 256, 0, stream>>>(bq, bk, bv, u16);
    bounds_kernel<<<17, 256, 0, stream>>>(h_emb, w_emb, u16);
    attn_kernel<<<dim3(48, 16), 256, 0, stream>>>(h_emb, w_emb, u16);
    out_kernel<<<dim3(72, 4, 2), 256, 0, stream>>>(bo, u16, out);
}